// Round 4
// baseline (206.902 us; speedup 1.0000x reference)
//
#include <hip/hip_runtime.h>
#include <hip/hip_bf16.h>

typedef short short8 __attribute__((ext_vector_type(8)));
typedef float f32x4 __attribute__((ext_vector_type(4)));

typedef const __attribute__((address_space(1))) unsigned int* gas_ptr;
typedef __attribute__((address_space(3))) unsigned int* las_ptr;
// async global->LDS, 16B/lane; LDS dest = wave-uniform base + lane*16 (m97/m104)
#define ASYNC16(g, l) __builtin_amdgcn_global_load_lds((gas_ptr)(g), (las_ptr)(l), 16, 0, 0)

__device__ __forceinline__ unsigned short f2bf(float f) {
    unsigned int u = __builtin_bit_cast(unsigned int, f);
    u += 0x7fff + ((u >> 16) & 1);   // RNE
    return (unsigned short)(u >> 16);
}
__device__ __forceinline__ float bf2f(unsigned short s) {
    unsigned int u = (unsigned int)s << 16;
    return __builtin_bit_cast(float, u);
}
// pack trunc-bf16(lo), trunc-bf16(hi) into one u32 via v_perm
__device__ __forceinline__ unsigned int pkbf_trunc(float lo, float hi) {
    return __builtin_amdgcn_perm(__builtin_bit_cast(unsigned int, hi),
                                 __builtin_bit_cast(unsigned int, lo), 0x07060302u);
}

// ---------------------------------------------------------------- cast x -> bf16
__global__ __launch_bounds__(256) void cast_f32_bf16(
    const float* __restrict__ in, unsigned short* __restrict__ out, int n)
{
    int i = (blockIdx.x * 256 + threadIdx.x) * 4;
    if (i >= n) return;
    float4 v = *(const float4*)(in + i);
    ushort4 o;
    o.x = f2bf(v.x); o.y = f2bf(v.y); o.z = f2bf(v.z); o.w = f2bf(v.w);
    *(ushort4*)(out + i) = o;
}

// ------------------------------------------------- transpose + cast W (K,N) -> Wt (N,K) bf16
__global__ __launch_bounds__(256) void transpose_cast(
    const float* __restrict__ w, unsigned short* __restrict__ wt, int K, int N)
{
    __shared__ unsigned short tile[64 * 65];
    int k0 = blockIdx.y * 64, n0 = blockIdx.x * 64;
    for (int i = threadIdx.x; i < 64 * 64; i += 256) {
        int r = i >> 6, c = i & 63;
        tile[r * 65 + c] = f2bf(w[(size_t)(k0 + r) * N + n0 + c]);
    }
    __syncthreads();
    for (int i = threadIdx.x; i < 64 * 64; i += 256) {
        int r = i >> 6, c = i & 63;
        wt[(size_t)(n0 + r) * K + k0 + c] = tile[c * 65 + r];
    }
}

// ---------------------------------------------------------------- GEMM: C = A * Bt^T + bias
// m97 structure: global_load_lds(16B) staging, unpadded stride-32 LDS, 2-barrier K-loop.
// QKV mode: cols [0,2048) -> qkv (stride 2048); cols [2048,3072) -> vT[(b*16+h)*64+d][s]

template<bool OUT_BF16, bool QKV>
__global__ __launch_bounds__(256, 3) void gemm_bt(
    const unsigned short* __restrict__ A,
    const unsigned short* __restrict__ Bt,
    const float* __restrict__ bias,
    void* __restrict__ C,
    unsigned short* __restrict__ vTp,
    int M, int N, int K)
{
    __shared__ __align__(16) unsigned short As[128 * 32];
    __shared__ __align__(16) unsigned short Bs[128 * 32];
    const int tid = threadIdx.x;
    const int lane = tid & 63;
    const int wave = tid >> 6;
    const int wr = wave >> 1, wc = wave & 1;
    const int m0 = blockIdx.x * 128, n0 = blockIdx.y * 128;
    const int fr = lane & 15, fq = lane >> 4;

    f32x4 acc[4][4] = {};

    const int grow = lane >> 2;
    const int gcol = (lane & 3) * 8;
    const unsigned short* Ag = A  + (size_t)(m0 + wave * 32 + grow) * K + gcol;
    const unsigned short* Bg = Bt + (size_t)(n0 + wave * 32 + grow) * K + gcol;
    unsigned short* AsW0 = As + (wave * 32) * 32;
    unsigned short* AsW1 = As + (wave * 32 + 16) * 32;
    unsigned short* BsW0 = Bs + (wave * 32) * 32;
    unsigned short* BsW1 = Bs + (wave * 32 + 16) * 32;

    for (int k0 = 0; k0 < K; k0 += 32) {
        __syncthreads();
        ASYNC16(Ag + k0,          AsW0);
        ASYNC16(Ag + 16 * K + k0, AsW1);
        ASYNC16(Bg + k0,          BsW0);
        ASYNC16(Bg + 16 * K + k0, BsW1);
        __syncthreads();

        short8 af[4], bfr[4];
#pragma unroll
        for (int i = 0; i < 4; i++)
            af[i] = *(const short8*)(As + (wr * 64 + i * 16 + fr) * 32 + fq * 8);
#pragma unroll
        for (int j = 0; j < 4; j++)
            bfr[j] = *(const short8*)(Bs + (wc * 64 + j * 16 + fr) * 32 + fq * 8);
#pragma unroll
        for (int i = 0; i < 4; i++)
#pragma unroll
            for (int j = 0; j < 4; j++)
                acc[i][j] = __builtin_amdgcn_mfma_f32_16x16x32_bf16(af[i], bfr[j], acc[i][j], 0, 0, 0);
    }

#pragma unroll
    for (int i = 0; i < 4; i++)
#pragma unroll
        for (int j = 0; j < 4; j++) {
            int col = n0 + wc * 64 + j * 16 + fr;
            float bv = bias[col];
            if (QKV && col >= 2048) {
                int hh = (col - 2048) >> 6, d = col & 63;
#pragma unroll
                for (int r = 0; r < 4; r++) {
                    int row = m0 + wr * 64 + i * 16 + fq * 4 + r;
                    int bb = row >> 11, s = row & 2047;
                    vTp[((size_t)(bb * 16 + hh) * 64 + d) * 2048 + s] = f2bf(acc[i][j][r] + bv);
                }
            } else {
                const int cstride = QKV ? 2048 : N;
#pragma unroll
                for (int r = 0; r < 4; r++) {
                    int row = m0 + wr * 64 + i * 16 + fq * 4 + r;
                    float v = acc[i][j][r] + bv;
                    if (OUT_BF16)
                        ((unsigned short*)C)[(size_t)row * cstride + col] = f2bf(v);
                    else
                        ((float*)C)[(size_t)row * cstride + col] = v;
                }
            }
        }
}

// ---------------------------------------------------------------- flash attention (causal, key-split)
// Block = (q-tile pair {p, 31-p}, key-half g). Fixed-shift softmax p=exp(s/8-8) makes
// key-split partials exactly additive: O = O0+O1, l = l0+l1 (reduce_attn combines).
// Ps layout: stride 64 + fq-rotation swizzle col' = (col + 16*fq) & 63 -> conflict-free
// scalar writes, optimally-phased b128 reads, 16B-aligned.

template<int RG0>
__device__ __forceinline__ void attn_step(
    const unsigned short* __restrict__ Ks0, const unsigned short* __restrict__ Ks1,
    const unsigned short* __restrict__ Vs0, const unsigned short* __restrict__ Vs1,
    unsigned short* __restrict__ Psw,
    const short8 (&qf)[2][2], const short8 ones,
    f32x4 (&o_acc)[2][4], f32x4 (&l_acc)[2],
    int j0, int fr, int fq,
    const int (&qrow0)[2], const bool (&diag)[2])
{
    f32x4 s[2][4];
#pragma unroll
    for (int rg = RG0; rg < 2; rg++)
#pragma unroll
        for (int t = 0; t < 4; t++)
            s[rg][t] = (f32x4){0.f, 0.f, 0.f, 0.f};

    // S = Q K^T
#pragma unroll
    for (int t = 0; t < 4; t++) {
        short8 kf0 = *(const short8*)(Ks0 + (t * 16 + fr) * 32 + fq * 8);
        short8 kf1 = *(const short8*)(Ks1 + (t * 16 + fr) * 32 + fq * 8);
#pragma unroll
        for (int rg = RG0; rg < 2; rg++) {
            s[rg][t] = __builtin_amdgcn_mfma_f32_16x16x32_bf16(qf[rg][0], kf0, s[rg][t], 0, 0, 0);
            s[rg][t] = __builtin_amdgcn_mfma_f32_16x16x32_bf16(qf[rg][1], kf1, s[rg][t], 0, 0, 0);
        }
    }

    // p = exp(s/8 - 8); trunc-pack via v_perm; stage to LDS (swizzled A-layout round trip)
#pragma unroll
    for (int rg = RG0; rg < 2; rg++) {
        unsigned short* prow = Psw + rg * (16 * 64);
#pragma unroll
        for (int t = 0; t < 4; t++) {
            float p[4];
#pragma unroll
            for (int r = 0; r < 4; r++) {
                float v = __expf(s[rg][t][r] * 0.125f - 8.0f);
                if (diag[rg] && (j0 + t * 16 + fr) > (qrow0[rg] + fq * 4 + r)) v = 0.f;
                p[r] = v;
            }
            unsigned int pk01 = pkbf_trunc(p[0], p[1]);
            unsigned int pk23 = pkbf_trunc(p[2], p[3]);
            int colp = (t * 16 + fr + 16 * fq) & 63;          // fq-rotation swizzle
            int base = (fq * 4) * 64 + colp;
            prow[base]       = (unsigned short)pk01;
            prow[base + 64]  = (unsigned short)(pk01 >> 16);
            prow[base + 128] = (unsigned short)pk23;
            prow[base + 192] = (unsigned short)(pk23 >> 16);
        }
    }

    // O += P V ; l += P 1   (Psw wave-private: same-wave LDS ordering, no barrier)
#pragma unroll
    for (int ks = 0; ks < 2; ks++) {
        const unsigned short* Vsb = ks ? Vs1 : Vs0;
        short8 pf[2];
#pragma unroll
        for (int rg = RG0; rg < 2; rg++) {
            int colp = (ks * 32 + fq * 8 + 16 * ((fr >> 2) & 3)) & 63;   // unswizzle for row fr
            pf[rg] = *(const short8*)(Psw + rg * (16 * 64) + fr * 64 + colp);
        }
#pragma unroll
        for (int t = 0; t < 4; t++) {
            short8 vf = *(const short8*)(Vsb + (t * 16 + fr) * 32 + fq * 8);
#pragma unroll
            for (int rg = RG0; rg < 2; rg++)
                o_acc[rg][t] = __builtin_amdgcn_mfma_f32_16x16x32_bf16(pf[rg], vf, o_acc[rg][t], 0, 0, 0);
        }
#pragma unroll
        for (int rg = RG0; rg < 2; rg++)
            l_acc[rg] = __builtin_amdgcn_mfma_f32_16x16x32_bf16(pf[rg], ones, l_acc[rg], 0, 0, 0);
    }
}

__global__ __launch_bounds__(256, 4) void flash_attn(
    const unsigned short* __restrict__ qkv,   // (B*S, 2048): Q | K
    const unsigned short* __restrict__ vT,    // (B*16 heads, 64 dims, 2048 keys)
    unsigned short* __restrict__ Opart,       // [2][B*S][1024] bf16 partial O
    float* __restrict__ lpart)                // [2][B*S][16] f32 partial l
{
    const int p = blockIdx.x;                 // q-tile pair {p, 31-p}
    const int g = blockIdx.y;                 // key half
    const int h = blockIdx.z & 15, b = blockIdx.z >> 4;
    const int qtA = p, qtB = 31 - p;
    const int tid = threadIdx.x, wave = tid >> 6, lane = tid & 63;
    const int fr = lane & 15, fq = lane >> 4;
    const size_t RS = 2048;

    const unsigned short* Qb = qkv + (size_t)b * 2048 * RS + h * 64;
    const unsigned short* Kb = Qb + 1024;
    const unsigned short* Vt = vT + (size_t)(b * 16 + h) * 64 * 2048;

    __shared__ __align__(16) unsigned short Ks[2][64 * 32];   // [dim-half][key][32 dims]
    __shared__ __align__(16) unsigned short Vs[2][64 * 32];   // [key-half][dim][32 keys]
    __shared__ __align__(16) unsigned short Ps[4][2 * 16 * 64];

    short8 qf[2][2];
    int qrow0[2];
#pragma unroll
    for (int rg = 0; rg < 2; rg++) {
        int qt = rg ? qtB : qtA;
        qrow0[rg] = qt * 64 + wave * 16;
        const unsigned short* qrow = Qb + (size_t)(qrow0[rg] + fr) * RS;
        qf[rg][0] = *(const short8*)(qrow + fq * 8);
        qf[rg][1] = *(const short8*)(qrow + 32 + fq * 8);
    }
    short8 ones;
#pragma unroll
    for (int e = 0; e < 8; e++) ones[e] = (short)0x3F80;

    f32x4 o_acc[2][4] = {};
    f32x4 l_acc[2] = {};

    const int grow = lane >> 2;
    const int gcol = (lane & 3) * 8;
    const unsigned short* Kg = Kb + (size_t)(wave * 16 + grow) * RS + gcol;
    const unsigned short* Vg = Vt + (size_t)(wave * 16 + grow) * 2048 + gcol;
    unsigned short* KsW0 = Ks[0] + (wave * 16) * 32;
    unsigned short* KsW1 = Ks[1] + (wave * 16) * 32;
    unsigned short* VsW0 = Vs[0] + (wave * 16) * 32;
    unsigned short* VsW1 = Vs[1] + (wave * 16) * 32;

    // balanced key split: units(half0)=16|17, units(half1)=17|16
    const int mid = (p >= 8) ? 8 : (16 - p);
    const int lo = g ? mid : 0;
    const int hi = g ? (32 - p) : mid;

    for (int jt = lo; jt < hi; jt++) {
        const int j0 = jt * 64;
        __syncthreads();
        ASYNC16(Kg + (size_t)j0 * RS,      KsW0);
        ASYNC16(Kg + (size_t)j0 * RS + 32, KsW1);
        ASYNC16(Vg + j0,      VsW0);
        ASYNC16(Vg + j0 + 32, VsW1);
        __syncthreads();

        bool diag[2] = { jt == qtA, jt == qtB };
        if (jt <= qtA)
            attn_step<0>(Ks[0], Ks[1], Vs[0], Vs[1], Ps[wave], qf, ones,
                         o_acc, l_acc, j0, fr, fq, qrow0, diag);
        else
            attn_step<1>(Ks[0], Ks[1], Vs[0], Vs[1], Ps[wave], qf, ones,
                         o_acc, l_acc, j0, fr, fq, qrow0, diag);
    }

    // write partials (bf16 O, f32 l)
    unsigned short* Og = Opart + (size_t)g * 4096 * 1024;
    float* lg = lpart + (size_t)g * 4096 * 16;
#pragma unroll
    for (int rg = 0; rg < 2; rg++) {
#pragma unroll
        for (int t = 0; t < 4; t++)
#pragma unroll
            for (int r = 0; r < 4; r++) {
                int row = qrow0[rg] + fq * 4 + r;
                Og[(size_t)(b * 2048 + row) * 1024 + h * 64 + t * 16 + fr] = f2bf(o_acc[rg][t][r]);
            }
        if (fr == 0) {
#pragma unroll
            for (int r = 0; r < 4; r++) {
                int row = qrow0[rg] + fq * 4 + r;
                lg[(size_t)(b * 2048 + row) * 16 + h] = l_acc[rg][r];
            }
        }
    }
}

// ---------------------------------------------------------------- combine key-split partials
__global__ __launch_bounds__(256) void reduce_attn(
    const unsigned short* __restrict__ Opart, const float* __restrict__ lpart,
    unsigned short* __restrict__ out)
{
    int i = (blockIdx.x * 256 + threadIdx.x) * 8;     // over 4096*1024
    int row = i >> 10, h = (i & 1023) >> 6;
    float lsum = lpart[(size_t)row * 16 + h] + lpart[(size_t)4096 * 16 + row * 16 + h];
    float inv = 1.0f / lsum;
    ushort4 a0 = *(const ushort4*)(Opart + i);
    ushort4 a1 = *(const ushort4*)(Opart + i + 4);
    ushort4 b0 = *(const ushort4*)(Opart + (size_t)4096 * 1024 + i);
    ushort4 b1 = *(const ushort4*)(Opart + (size_t)4096 * 1024 + i + 4);
    ushort4 o0, o1;
    o0.x = f2bf((bf2f(a0.x) + bf2f(b0.x)) * inv);
    o0.y = f2bf((bf2f(a0.y) + bf2f(b0.y)) * inv);
    o0.z = f2bf((bf2f(a0.z) + bf2f(b0.z)) * inv);
    o0.w = f2bf((bf2f(a0.w) + bf2f(b0.w)) * inv);
    o1.x = f2bf((bf2f(a1.x) + bf2f(b1.x)) * inv);
    o1.y = f2bf((bf2f(a1.y) + bf2f(b1.y)) * inv);
    o1.z = f2bf((bf2f(a1.z) + bf2f(b1.z)) * inv);
    o1.w = f2bf((bf2f(a1.w) + bf2f(b1.w)) * inv);
    *(ushort4*)(out + i) = o0;
    *(ushort4*)(out + i + 4) = o1;
}

// ----------------------------------------------------------------
extern "C" void kernel_launch(void* const* d_in, const int* in_sizes, int n_in,
                              void* d_out, int out_size, void* d_ws, size_t ws_size,
                              hipStream_t stream) {
    const float* x      = (const float*)d_in[0];
    const float* w_qkv  = (const float*)d_in[1];
    const float* b_qkv  = (const float*)d_in[2];
    const float* w_out  = (const float*)d_in[3];
    const float* b_out  = (const float*)d_in[4];
    float* out = (float*)d_out;

    char* ws = (char*)d_ws;
    unsigned short* x_b    = (unsigned short*)(ws);                        //  8 MB
    unsigned short* wqkv_t = (unsigned short*)(ws + 8u  * 1024 * 1024);    //  6 MB
    unsigned short* wout_t = (unsigned short*)(ws + 14u * 1024 * 1024);    //  2 MB
    unsigned short* qkv    = (unsigned short*)(ws + 16u * 1024 * 1024);    // 16 MB (Q|K stride 2048)
    unsigned short* attn   = (unsigned short*)(ws + 32u * 1024 * 1024);    //  8 MB
    unsigned short* vT     = (unsigned short*)(ws + 40u * 1024 * 1024);    //  8 MB
    unsigned short* Opart  = (unsigned short*)(ws + 48u * 1024 * 1024);    // 16 MB (2 halves)
    float*          lpart  = (float*)         (ws + 64u * 1024 * 1024);    // 512 KB

    cast_f32_bf16<<<4096, 256, 0, stream>>>(x, x_b, 2 * 2048 * 1024);
    transpose_cast<<<dim3(48, 16), 256, 0, stream>>>(w_qkv, wqkv_t, 1024, 3072);
    transpose_cast<<<dim3(16, 16), 256, 0, stream>>>(w_out, wout_t, 1024, 1024);
    gemm_bt<true, true ><<<dim3(32, 24), 256, 0, stream>>>(x_b,  wqkv_t, b_qkv, qkv, vT, 4096, 3072, 1024);
    flash_attn<<<dim3(16, 2, 32), 256, 0, stream>>>(qkv, vT, Opart, lpart);
    reduce_attn<<<2048, 256, 0, stream>>>(Opart, lpart, attn);
    gemm_bt<false, false><<<dim3(32, 8),  256, 0, stream>>>(attn, wout_t, b_out, out, nullptr, 4096, 1024, 1024);
}

// Round 5
// 193.036 us; speedup vs baseline: 1.0718x; 1.0718x over previous
//
#include <hip/hip_runtime.h>
#include <hip/hip_bf16.h>

typedef short short8 __attribute__((ext_vector_type(8)));
typedef float f32x4 __attribute__((ext_vector_type(4)));

typedef const __attribute__((address_space(1))) unsigned int* gas_ptr;
typedef __attribute__((address_space(3))) unsigned int* las_ptr;
// async global->LDS, 16B/lane; LDS dest = wave-uniform base + lane*16 (m97/m104)
#define ASYNC16(g, l) __builtin_amdgcn_global_load_lds((gas_ptr)(g), (las_ptr)(l), 16, 0, 0)

__device__ __forceinline__ unsigned short f2bf(float f) {
    unsigned int u = __builtin_bit_cast(unsigned int, f);
    u += 0x7fff + ((u >> 16) & 1);   // RNE
    return (unsigned short)(u >> 16);
}
__device__ __forceinline__ float bf2f(unsigned short s) {
    unsigned int u = (unsigned int)s << 16;
    return __builtin_bit_cast(float, u);
}
__device__ __forceinline__ unsigned int pkbf_trunc(float lo, float hi) {
    return __builtin_amdgcn_perm(__builtin_bit_cast(unsigned int, hi),
                                 __builtin_bit_cast(unsigned int, lo), 0x07060302u);
}

// ---------------------------------------------------------------- fused prep:
// blocks [0,4096): cast x->bf16 ; [4096,4864): transpose w_qkv ; [4864,5120): transpose w_out
__device__ __forceinline__ void transpose_tile(
    const float* __restrict__ w, unsigned short* __restrict__ wt,
    int K, int N, int k0, int n0, unsigned short* tile)
{
    for (int i = threadIdx.x; i < 64 * 64; i += 256) {
        int r = i >> 6, c = i & 63;
        tile[r * 65 + c] = f2bf(w[(size_t)(k0 + r) * N + n0 + c]);
    }
    __syncthreads();
    for (int i = threadIdx.x; i < 64 * 64; i += 256) {
        int r = i >> 6, c = i & 63;
        wt[(size_t)(n0 + r) * K + k0 + c] = tile[c * 65 + r];
    }
}

__global__ __launch_bounds__(256) void prep(
    const float* __restrict__ x, const float* __restrict__ w_qkv,
    const float* __restrict__ w_out,
    unsigned short* __restrict__ x_b, unsigned short* __restrict__ wqkv_t,
    unsigned short* __restrict__ wout_t)
{
    __shared__ unsigned short tile[64 * 65];
    int bid = blockIdx.x;
    if (bid < 4096) {
        int i = (bid * 256 + threadIdx.x) * 4;
        float4 v = *(const float4*)(x + i);
        ushort4 o;
        o.x = f2bf(v.x); o.y = f2bf(v.y); o.z = f2bf(v.z); o.w = f2bf(v.w);
        *(ushort4*)(x_b + i) = o;
    } else if (bid < 4096 + 768) {
        int t = bid - 4096;
        transpose_tile(w_qkv, wqkv_t, 1024, 3072, (t / 48) * 64, (t % 48) * 64, tile);
    } else {
        int t = bid - 4864;
        transpose_tile(w_out, wout_t, 1024, 1024, (t >> 4) * 64, (t & 15) * 64, tile);
    }
}

// ---------------------------------------------------------------- GEMM: C = A * Bt^T + bias
// m97 structure. QKV mode: cols [0,2048) -> qkv (stride 2048); cols [2048,3072) -> vT

template<bool OUT_BF16, bool QKV>
__global__ __launch_bounds__(256, 3) void gemm_bt(
    const unsigned short* __restrict__ A,
    const unsigned short* __restrict__ Bt,
    const float* __restrict__ bias,
    void* __restrict__ C,
    unsigned short* __restrict__ vTp,
    int M, int N, int K)
{
    __shared__ __align__(16) unsigned short As[128 * 32];
    __shared__ __align__(16) unsigned short Bs[128 * 32];
    const int tid = threadIdx.x;
    const int lane = tid & 63;
    const int wave = tid >> 6;
    const int wr = wave >> 1, wc = wave & 1;
    const int m0 = blockIdx.x * 128, n0 = blockIdx.y * 128;
    const int fr = lane & 15, fq = lane >> 4;

    f32x4 acc[4][4] = {};

    const int grow = lane >> 2;
    const int gcol = (lane & 3) * 8;
    const unsigned short* Ag = A  + (size_t)(m0 + wave * 32 + grow) * K + gcol;
    const unsigned short* Bg = Bt + (size_t)(n0 + wave * 32 + grow) * K + gcol;
    unsigned short* AsW0 = As + (wave * 32) * 32;
    unsigned short* AsW1 = As + (wave * 32 + 16) * 32;
    unsigned short* BsW0 = Bs + (wave * 32) * 32;
    unsigned short* BsW1 = Bs + (wave * 32 + 16) * 32;

    for (int k0 = 0; k0 < K; k0 += 32) {
        __syncthreads();
        ASYNC16(Ag + k0,          AsW0);
        ASYNC16(Ag + 16 * K + k0, AsW1);
        ASYNC16(Bg + k0,          BsW0);
        ASYNC16(Bg + 16 * K + k0, BsW1);
        __syncthreads();

        short8 af[4], bfr[4];
#pragma unroll
        for (int i = 0; i < 4; i++)
            af[i] = *(const short8*)(As + (wr * 64 + i * 16 + fr) * 32 + fq * 8);
#pragma unroll
        for (int j = 0; j < 4; j++)
            bfr[j] = *(const short8*)(Bs + (wc * 64 + j * 16 + fr) * 32 + fq * 8);
#pragma unroll
        for (int i = 0; i < 4; i++)
#pragma unroll
            for (int j = 0; j < 4; j++)
                acc[i][j] = __builtin_amdgcn_mfma_f32_16x16x32_bf16(af[i], bfr[j], acc[i][j], 0, 0, 0);
    }

#pragma unroll
    for (int i = 0; i < 4; i++)
#pragma unroll
        for (int j = 0; j < 4; j++) {
            int col = n0 + wc * 64 + j * 16 + fr;
            float bv = bias[col];
            if (QKV && col >= 2048) {
                int hh = (col - 2048) >> 6, d = col & 63;
#pragma unroll
                for (int r = 0; r < 4; r++) {
                    int row = m0 + wr * 64 + i * 16 + fq * 4 + r;
                    int bb = row >> 11, s = row & 2047;
                    vTp[((size_t)(bb * 16 + hh) * 64 + d) * 2048 + s] = f2bf(acc[i][j][r] + bv);
                }
            } else {
                const int cstride = QKV ? 2048 : N;
#pragma unroll
                for (int r = 0; r < 4; r++) {
                    int row = m0 + wr * 64 + i * 16 + fq * 4 + r;
                    float v = acc[i][j][r] + bv;
                    if (OUT_BF16)
                        ((unsigned short*)C)[(size_t)row * cstride + col] = f2bf(v);
                    else
                        ((float*)C)[(size_t)row * cstride + col] = v;
                }
            }
        }
}

// ---------------------------------------------------------------- flash attention (causal, key-split)
// 128-thread blocks (2 waves). Wave owns 64 q-rows: rg0,1 = tile p rows [w*32,+32),
// rg2,3 = tile 31-p rows [w*32,+32). K/V frags read once per wave serve all 4 rg
// (LDS reads/q-row: 0.375 b128 vs 0.625 in the 4-wave version — LDS pipe is the cap).
// Fixed-shift softmax p=exp(s/8-8) => key-split partials exactly additive.

template<int RG0>   // 0: all 4 rg active; 2: only rg2,3 (jt > p)
__device__ __forceinline__ void attn_step(
    const unsigned short* __restrict__ Ks0, const unsigned short* __restrict__ Ks1,
    const unsigned short* __restrict__ Vs0, const unsigned short* __restrict__ Vs1,
    unsigned short* __restrict__ Psw,
    const short8 (&qf)[4][2], const short8 ones,
    f32x4 (&o_acc)[4][4], f32x4 (&l_acc)[4],
    int j0, int fr, int fq,
    const int (&qrow0)[4], bool diagA, bool diagB)
{
    short8 kf[4][2];
#pragma unroll
    for (int t = 0; t < 4; t++) {
        kf[t][0] = *(const short8*)(Ks0 + (t * 16 + fr) * 32 + fq * 8);
        kf[t][1] = *(const short8*)(Ks1 + (t * 16 + fr) * 32 + fq * 8);
    }

#pragma unroll
    for (int rg = RG0; rg < 4; rg++) {
        f32x4 s[4];
#pragma unroll
        for (int t = 0; t < 4; t++) {
            s[t] = (f32x4){0.f, 0.f, 0.f, 0.f};
            s[t] = __builtin_amdgcn_mfma_f32_16x16x32_bf16(qf[rg][0], kf[t][0], s[t], 0, 0, 0);
            s[t] = __builtin_amdgcn_mfma_f32_16x16x32_bf16(qf[rg][1], kf[t][1], s[t], 0, 0, 0);
        }
        const bool diag = (rg < 2) ? diagA : diagB;
        unsigned short* prow = Psw + rg * (16 * 64);
        if (diag) {   // wave-uniform branch: mask cost only on 1-2 tiles of ~16
#pragma unroll
            for (int t = 0; t < 4; t++) {
                float p[4];
#pragma unroll
                for (int r = 0; r < 4; r++) {
                    float v = __expf(s[t][r] * 0.125f - 8.0f);
                    if ((j0 + t * 16 + fr) > (qrow0[rg] + fq * 4 + r)) v = 0.f;
                    p[r] = v;
                }
                unsigned int pk01 = pkbf_trunc(p[0], p[1]);
                unsigned int pk23 = pkbf_trunc(p[2], p[3]);
                int base = (fq * 4) * 64 + ((t * 16 + fr + 16 * fq) & 63);
                prow[base]       = (unsigned short)pk01;
                prow[base + 64]  = (unsigned short)(pk01 >> 16);
                prow[base + 128] = (unsigned short)pk23;
                prow[base + 192] = (unsigned short)(pk23 >> 16);
            }
        } else {
#pragma unroll
            for (int t = 0; t < 4; t++) {
                float p[4];
#pragma unroll
                for (int r = 0; r < 4; r++)
                    p[r] = __expf(s[t][r] * 0.125f - 8.0f);
                unsigned int pk01 = pkbf_trunc(p[0], p[1]);
                unsigned int pk23 = pkbf_trunc(p[2], p[3]);
                int base = (fq * 4) * 64 + ((t * 16 + fr + 16 * fq) & 63);
                prow[base]       = (unsigned short)pk01;
                prow[base + 64]  = (unsigned short)(pk01 >> 16);
                prow[base + 128] = (unsigned short)pk23;
                prow[base + 192] = (unsigned short)(pk23 >> 16);
            }
        }
    }

    // O += P V ; l += P 1   (Psw wave-private: same-wave LDS ordering, no barrier)
#pragma unroll
    for (int ks = 0; ks < 2; ks++) {
        const unsigned short* Vsb = ks ? Vs1 : Vs0;
        const int colp = (ks * 32 + fq * 8 + 16 * ((fr >> 2) & 3)) & 63;  // unswizzle
        short8 pf[4];
#pragma unroll
        for (int rg = RG0; rg < 4; rg++)
            pf[rg] = *(const short8*)(Psw + rg * (16 * 64) + fr * 64 + colp);
#pragma unroll
        for (int t = 0; t < 4; t++) {
            short8 vf = *(const short8*)(Vsb + (t * 16 + fr) * 32 + fq * 8);
#pragma unroll
            for (int rg = RG0; rg < 4; rg++)
                o_acc[rg][t] = __builtin_amdgcn_mfma_f32_16x16x32_bf16(pf[rg], vf, o_acc[rg][t], 0, 0, 0);
        }
#pragma unroll
        for (int rg = RG0; rg < 4; rg++)
            l_acc[rg] = __builtin_amdgcn_mfma_f32_16x16x32_bf16(pf[rg], ones, l_acc[rg], 0, 0, 0);
    }
}

__global__ __launch_bounds__(128, 2) void flash_attn(
    const unsigned short* __restrict__ qkv,   // (B*S, 2048): Q | K
    const unsigned short* __restrict__ vT,    // (B*16 heads, 64 dims, 2048 keys)
    unsigned short* __restrict__ Opart,       // [2][B*S][1024] bf16 partial O
    float* __restrict__ lpart)                // [2][B*S][16] f32 partial l
{
    const int p = blockIdx.x;                 // q-tile pair {p, 31-p}
    const int g = blockIdx.y;                 // key half
    const int h = blockIdx.z & 15, b = blockIdx.z >> 4;
    const int tid = threadIdx.x, wave = tid >> 6, lane = tid & 63;
    const int fr = lane & 15, fq = lane >> 4;
    const size_t RS = 2048;

    const unsigned short* Qb = qkv + (size_t)b * 2048 * RS + h * 64;
    const unsigned short* Kb = Qb + 1024;
    const unsigned short* Vt = vT + (size_t)(b * 16 + h) * 64 * 2048;

    __shared__ __align__(16) unsigned short Ks[2][64 * 32];   // [dim-half][key][32 dims]
    __shared__ __align__(16) unsigned short Vs[2][64 * 32];   // [key-half][dim][32 keys]
    __shared__ __align__(16) unsigned short Ps[2][4 * 16 * 64];

    short8 qf[4][2];
    int qrow0[4];
#pragma unroll
    for (int rg = 0; rg < 4; rg++) {
        int qt = (rg < 2) ? p : (31 - p);
        qrow0[rg] = qt * 64 + wave * 32 + (rg & 1) * 16;
        const unsigned short* qrow = Qb + (size_t)(qrow0[rg] + fr) * RS;
        qf[rg][0] = *(const short8*)(qrow + fq * 8);
        qf[rg][1] = *(const short8*)(qrow + 32 + fq * 8);
    }
    short8 ones;
#pragma unroll
    for (int e = 0; e < 8; e++) ones[e] = (short)0x3F80;

    f32x4 o_acc[4][4] = {};
    f32x4 l_acc[4] = {};

    const int grow = lane >> 2;
    const int gcol = (lane & 3) * 8;
    const unsigned short* Kg = Kb + (size_t)(wave * 32 + grow) * RS + gcol;
    const unsigned short* Vg = Vt + (size_t)(wave * 32 + grow) * 2048 + gcol;
    unsigned short* KsW00 = Ks[0] + (wave * 32) * 32;
    unsigned short* KsW01 = Ks[0] + (wave * 32 + 16) * 32;
    unsigned short* KsW10 = Ks[1] + (wave * 32) * 32;
    unsigned short* KsW11 = Ks[1] + (wave * 32 + 16) * 32;
    unsigned short* VsW00 = Vs[0] + (wave * 32) * 32;
    unsigned short* VsW01 = Vs[0] + (wave * 32 + 16) * 32;
    unsigned short* VsW10 = Vs[1] + (wave * 32) * 32;
    unsigned short* VsW11 = Vs[1] + (wave * 32 + 16) * 32;

    // balanced key split over weighted units (4 while jt<=p, else 2): 34/32
    const int mid = (p >= 8) ? 8 : (16 - p);
    const int lo = g ? mid : 0;
    const int hi = g ? (32 - p) : mid;

    for (int jt = lo; jt < hi; jt++) {
        const int j0 = jt * 64;
        __syncthreads();
        ASYNC16(Kg + (size_t)j0 * RS,               KsW00);
        ASYNC16(Kg + (size_t)(j0 + 16) * RS,        KsW01);
        ASYNC16(Kg + (size_t)j0 * RS + 32,          KsW10);
        ASYNC16(Kg + (size_t)(j0 + 16) * RS + 32,   KsW11);
        ASYNC16(Vg + j0,               VsW00);
        ASYNC16(Vg + 16 * 2048 + j0,   VsW01);
        ASYNC16(Vg + j0 + 32,          VsW10);
        ASYNC16(Vg + 16 * 2048 + j0 + 32, VsW11);
        __syncthreads();

        bool diagA = (jt == p), diagB = (jt == 31 - p);
        if (jt <= p)
            attn_step<0>(Ks[0], Ks[1], Vs[0], Vs[1], Ps[wave], qf, ones,
                         o_acc, l_acc, j0, fr, fq, qrow0, diagA, diagB);
        else
            attn_step<2>(Ks[0], Ks[1], Vs[0], Vs[1], Ps[wave], qf, ones,
                         o_acc, l_acc, j0, fr, fq, qrow0, diagA, diagB);
    }

    // write partials (bf16 O, f32 l)
    unsigned short* Og = Opart + (size_t)g * 4096 * 1024;
    float* lg = lpart + (size_t)g * 4096 * 16;
#pragma unroll
    for (int rg = 0; rg < 4; rg++) {
#pragma unroll
        for (int t = 0; t < 4; t++)
#pragma unroll
            for (int r = 0; r < 4; r++) {
                int row = qrow0[rg] + fq * 4 + r;
                Og[(size_t)(b * 2048 + row) * 1024 + h * 64 + t * 16 + fr] = f2bf(o_acc[rg][t][r]);
            }
        if (fr == 0) {
#pragma unroll
            for (int r = 0; r < 4; r++) {
                int row = qrow0[rg] + fq * 4 + r;
                lg[(size_t)(b * 2048 + row) * 16 + h] = l_acc[rg][r];
            }
        }
    }
}

// ---------------------------------------------------------------- combine key-split partials
__global__ __launch_bounds__(256) void reduce_attn(
    const unsigned short* __restrict__ Opart, const float* __restrict__ lpart,
    unsigned short* __restrict__ out)
{
    int i = (blockIdx.x * 256 + threadIdx.x) * 8;     // over 4096*1024
    int row = i >> 10, h = (i & 1023) >> 6;
    float lsum = lpart[(size_t)row * 16 + h] + lpart[(size_t)4096 * 16 + row * 16 + h];
    float inv = 1.0f / lsum;
    ushort4 a0 = *(const ushort4*)(Opart + i);
    ushort4 a1 = *(const ushort4*)(Opart + i + 4);
    ushort4 b0 = *(const ushort4*)(Opart + (size_t)4096 * 1024 + i);
    ushort4 b1 = *(const ushort4*)(Opart + (size_t)4096 * 1024 + i + 4);
    ushort4 o0, o1;
    o0.x = f2bf((bf2f(a0.x) + bf2f(b0.x)) * inv);
    o0.y = f2bf((bf2f(a0.y) + bf2f(b0.y)) * inv);
    o0.z = f2bf((bf2f(a0.z) + bf2f(b0.z)) * inv);
    o0.w = f2bf((bf2f(a0.w) + bf2f(b0.w)) * inv);
    o1.x = f2bf((bf2f(a1.x) + bf2f(b1.x)) * inv);
    o1.y = f2bf((bf2f(a1.y) + bf2f(b1.y)) * inv);
    o1.z = f2bf((bf2f(a1.z) + bf2f(b1.z)) * inv);
    o1.w = f2bf((bf2f(a1.w) + bf2f(b1.w)) * inv);
    *(ushort4*)(out + i) = o0;
    *(ushort4*)(out + i + 4) = o1;
}

// ----------------------------------------------------------------
extern "C" void kernel_launch(void* const* d_in, const int* in_sizes, int n_in,
                              void* d_out, int out_size, void* d_ws, size_t ws_size,
                              hipStream_t stream) {
    const float* x      = (const float*)d_in[0];
    const float* w_qkv  = (const float*)d_in[1];
    const float* b_qkv  = (const float*)d_in[2];
    const float* w_out  = (const float*)d_in[3];
    const float* b_out  = (const float*)d_in[4];
    float* out = (float*)d_out;

    char* ws = (char*)d_ws;
    unsigned short* x_b    = (unsigned short*)(ws);                        //  8 MB
    unsigned short* wqkv_t = (unsigned short*)(ws + 8u  * 1024 * 1024);    //  6 MB
    unsigned short* wout_t = (unsigned short*)(ws + 14u * 1024 * 1024);    //  2 MB
    unsigned short* qkv    = (unsigned short*)(ws + 16u * 1024 * 1024);    // 16 MB (Q|K stride 2048)
    unsigned short* attn   = (unsigned short*)(ws + 32u * 1024 * 1024);    //  8 MB
    unsigned short* vT     = (unsigned short*)(ws + 40u * 1024 * 1024);    //  8 MB
    unsigned short* Opart  = (unsigned short*)(ws + 48u * 1024 * 1024);    // 16 MB (2 halves)
    float*          lpart  = (float*)         (ws + 64u * 1024 * 1024);    // 512 KB

    prep<<<5120, 256, 0, stream>>>(x, w_qkv, w_out, x_b, wqkv_t, wout_t);
    gemm_bt<true, true ><<<dim3(32, 24), 256, 0, stream>>>(x_b,  wqkv_t, b_qkv, qkv, vT, 4096, 3072, 1024);
    flash_attn<<<dim3(16, 2, 32), 128, 0, stream>>>(qkv, vT, Opart, lpart);
    reduce_attn<<<2048, 256, 0, stream>>>(Opart, lpart, attn);
    gemm_bt<false, false><<<dim3(32, 8),  256, 0, stream>>>(attn, wout_t, b_out, out, nullptr, 4096, 1024, 1024);
}